// Round 6
// baseline (322.814 us; speedup 1.0000x reference)
//
#include <hip/hip_runtime.h>
#include <math.h>

// TOF PET forward projection.
// R3: 97us main, FETCH 215MB (L2 thrash). R4: Morton sort -> FETCH 26MB, but
// wave-per-LOR mapping is VALU-bound at 113us (VALUBusy ~110%).
// R5: thread-per-LOR over the sorted order: setup (8 IEEE divs) amortized
// x64 per wave, no shuffle reduction, full lane utilization in the sample
// loop. Sort key = Morton(TOF-center cell) x window-length class (2 bits) so
// waves get similar loop trip counts. Gather locality preserved (64 rays of a
// wave share a ~25mm neighborhood).
// Index-path math is STRICTLY UNFUSED exact-rn f32 (numpy semantics) — DO NOT
// approximate or contract (R0-R2: FMA/ulp deviations => voxel flips =>
// absmax 0.14 > 0.071 threshold). fp contract(off) + plain ops + plain '/'.

#define NB_POS 4096          // 16^3 Morton cells, 25 mm
#define NCLS   4             // window-length classes (32-sample bins)
#define NBUCK  (NB_POS * NCLS)

__device__ __forceinline__ int morton4(int x, int y, int z) {
    int m = 0;
#pragma unroll
    for (int b = 0; b < 4; ++b) {
        m |= ((x >> b) & 1) << (3 * b + 0);
        m |= ((y >> b) & 1) << (3 * b + 1);
        m |= ((z >> b) & 1) << (3 * b + 2);
    }
    return m;
}

__global__ void bucket_kernel(const float* __restrict__ lors,
                              int* __restrict__ counts,
                              int* __restrict__ tmp, int n) {
    int i = blockIdx.x * 256 + threadIdx.x;
    if (i >= n) return;
    const float* lp = lors + (size_t)i * 7;
    float p1x = lp[0], p1y = lp[1], p1z = lp[2];
    float dx = lp[3] - p1x, dy = lp[4] - p1y, dz = lp[5] - p1z;
    float tt = lp[6];
    float L = sqrtf(dx * dx + dy * dy + dz * dz);

    const float eps = 1e-8f;
    float sdx = (fabsf(dx) < eps) ? eps : dx;
    float sdy = (fabsf(dy) < eps) ? eps : dy;
    float sdz = (fabsf(dz) < eps) ? eps : dz;
    float tax = (-200.f - p1x) / sdx, tbx = (200.f - p1x) / sdx;
    float tay = (-200.f - p1y) / sdy, tby = (200.f - p1y) / sdy;
    float taz = (-200.f - p1z) / sdz, tbz = (200.f - p1z) / sdz;
    float tmin = fmaxf(fmaxf(fmaxf(fminf(tax, tbx), fminf(tay, tby)),
                             fminf(taz, tbz)), 0.f);
    float tmax = fminf(fminf(fminf(fmaxf(tax, tbx), fmaxf(tay, tby)),
                             fmaxf(taz, tbz)), 1.f);

    unsigned key;
    if (!(tmax > tmin) || !(L > 0.f)) {
        key = NBUCK - 1;                       // invalids grouped at the end
    } else {
        float span = tmax - tmin;
        // in-box TOF-center point -> 25mm Morton cell (sort key only; approx ok)
        float tc = fminf(fmaxf(0.5f + tt / L, tmin), tmax);
        float px = p1x + tc * dx, py = p1y + tc * dy, pz = p1z + tc * dz;
        int cx = (int)fminf(fmaxf((px + 200.f) * 0.04f, 0.f), 15.f);
        int cy = (int)fminf(fmaxf((py + 200.f) * 0.04f, 0.f), 15.f);
        int cz = (int)fminf(fmaxf((pz + 200.f) * 0.04f, 0.f), 15.f);
        // window length (samples) -> 2-bit class, equalizes wave trip counts
        float jl = ((0.5f + (tt - 90.f) / L) - tmin) / span * 128.f;
        float jh = ((0.5f + (tt + 90.f) / L) - tmin) / span * 128.f;
        jl = fmaxf(jl, 0.f); jh = fminf(jh, 128.f);
        float wlen = fmaxf(jh - jl, 0.f);
        int cls = min(NCLS - 1, (int)(wlen * (1.f / 32.f)));
        key = ((unsigned)morton4(cx, cy, cz) << 2) | (unsigned)cls;
    }
    unsigned r = (unsigned)atomicAdd(&counts[key], 1);
    tmp[i] = (int)((key << 18) | r);           // n < 2^18
}

__global__ void scan_kernel(const int* __restrict__ counts,
                            int* __restrict__ offsets) {
    __shared__ int s[1024];
    int t = threadIdx.x;
    int base = t * (NBUCK / 1024);
    int local[NBUCK / 1024];
    int sum = 0;
#pragma unroll
    for (int i = 0; i < NBUCK / 1024; ++i) { local[i] = counts[base + i]; sum += local[i]; }
    s[t] = sum;
    __syncthreads();
    for (int off = 1; off < 1024; off <<= 1) {
        int v = (t >= off) ? s[t - off] : 0;
        __syncthreads();
        s[t] += v;
        __syncthreads();
    }
    int excl = (t == 0) ? 0 : s[t - 1];
#pragma unroll
    for (int i = 0; i < NBUCK / 1024; ++i) { offsets[base + i] = excl; excl += local[i]; }
}

__global__ void scatter_kernel(const int* __restrict__ tmp,
                               const int* __restrict__ offsets,
                               int* __restrict__ perm, int n) {
    int i = blockIdx.x * 256 + threadIdx.x;
    if (i >= n) return;
    unsigned v = (unsigned)tmp[i];
    perm[offsets[v >> 18] + (v & 0x3FFFFu)] = i;
}

__global__ __launch_bounds__(256) void proj_kernel(
    const float* __restrict__ image,
    const float* __restrict__ lors,
    float* __restrict__ out,
    const int* __restrict__ perm,
    int n_lors, int chunks)
{
#pragma clang fp contract(off)
    // XCD swizzle: block b -> XCD (b&7) works the (b&7)-th chunk of sorted order
    const int b = blockIdx.x;
    const int sb = (b & 7) * chunks + (b >> 3);
    const int i = sb * 256 + (int)threadIdx.x;
    if (i >= n_lors) return;
    const int lor = perm ? perm[i] : i;

    const float* lp = lors + (size_t)lor * 7;
    const float p1x = lp[0], p1y = lp[1], p1z = lp[2];
    const float p2x = lp[3], p2y = lp[4], p2z = lp[5];
    const float ttof = lp[6];

    const float dx = p2x - p1x;
    const float dy = p2y - p1y;
    const float dz = p2z - p1z;

    // numpy order, unfused
    const float L = sqrtf(((dx * dx) + (dy * dy)) + (dz * dz));

    const float eps = 1e-8f;
    const float sdx = (fabsf(dx) < eps) ? eps : dx;
    const float sdy = (fabsf(dy) < eps) ? eps : dy;
    const float sdz = (fabsf(dz) < eps) ? eps : dz;

    // slab intersection, exact rn division (feeds the index path!)
    const float tax = (-200.0f - p1x) / sdx;
    const float tbx = ( 200.0f - p1x) / sdx;
    const float tay = (-200.0f - p1y) / sdy;
    const float tby = ( 200.0f - p1y) / sdy;
    const float taz = (-200.0f - p1z) / sdz;
    const float tbz = ( 200.0f - p1z) / sdz;

    const float tmin = fmaxf(fmaxf(fmaxf(fminf(tax, tbx), fminf(tay, tby)),
                                   fminf(taz, tbz)), 0.0f);
    const float tmax = fminf(fminf(fminf(fmaxf(tax, tbx), fmaxf(tay, tby)),
                                   fmaxf(taz, tbz)), 1.0f);
    const float span = fmaxf(tmax - tmin, 0.0f);

    if (!(tmax > tmin)) { out[lor] = 0.0f; return; }

    // Closed-form sample range of TOF window (+-2 slop, validated R4; exact
    // per-sample test retained below -> bit-identical to full scan).
    int jlo = 0, jhi = 127;
    if (L > 0.0f) {
        const float tlo = 0.5f + (ttof - 90.0f) / L;
        const float thi = 0.5f + (ttof + 90.0f) / L;
        float jl = ((tlo - tmin) / span) * 128.0f - 0.5f;
        float jh = ((thi - tmin) / span) * 128.0f - 0.5f;
        jl = fminf(fmaxf(jl - 2.0f, 0.0f), 127.0f);
        jh = fminf(fmaxf(jh + 2.0f, -1.0f), 127.0f);
        jlo = (int)jl;
        jhi = (int)ceilf(jh);
        if (jhi > 127) jhi = 127;
    }

    float acc = 0.0f;
    for (int j = jlo; j <= jhi; ++j) {
        const float frac = ((float)j + 0.5f) / 128.0f;       // exact
        const float t = tmin + (frac * span);                 // UNFUSED
        const float dev = ((t - 0.5f) * L) - ttof;            // unfused

        if (fabsf(dev) <= 90.0f) {
            const float px = p1x + (t * dx);                  // UNFUSED
            const float py = p1y + (t * dy);
            const float pz = p1z + (t * dz);
            int vx = (int)floorf((px + 200.0f) / 3.125f);     // exact rn div
            int vy = (int)floorf((py + 200.0f) / 3.125f);
            int vz = (int)floorf((pz + 200.0f) / 3.125f);
            vx = min(max(vx, 0), 127);
            vy = min(max(vy, 0), 127);
            vz = min(max(vz, 0), 127);

            const float val = image[(((vx << 7) | vy) << 7) | vz];

            const float w = 0.06649038f *
                            __expf(((-0.5f * dev) * dev) / 900.0f);
            acc += val * w;
        }
    }

    const float step = (span * L) / 128.0f;
    out[lor] = acc * step;
}

extern "C" void kernel_launch(void* const* d_in, const int* in_sizes, int n_in,
                              void* d_out, int out_size, void* d_ws, size_t ws_size,
                              hipStream_t stream) {
    const float* image = (const float*)d_in[0];   // 128^3 fp32
    const float* lors  = (const float*)d_in[1];   // N x 7 fp32
    float* out = (float*)d_out;                   // N fp32
    const int n = in_sizes[1] / 7;

    int* counts  = (int*)d_ws;
    int* offsets = counts + NBUCK;
    int* tmp     = offsets + NBUCK;
    int* perm    = tmp + n;
    const size_t need = (size_t)(2 * NBUCK + 2 * n) * sizeof(int);
    const bool do_sort = (ws_size >= need) && (n < (1 << 18));

    const int nblocks = (n + 255) / 256;
    const int nb8 = ((nblocks + 7) / 8) * 8;

    if (do_sort) {
        hipMemsetAsync(counts, 0, NBUCK * sizeof(int), stream);
        bucket_kernel<<<(n + 255) / 256, 256, 0, stream>>>(lors, counts, tmp, n);
        scan_kernel<<<1, 1024, 0, stream>>>(counts, offsets);
        scatter_kernel<<<(n + 255) / 256, 256, 0, stream>>>(tmp, offsets, perm, n);
    }
    proj_kernel<<<nb8, 256, 0, stream>>>(image, lors, out,
                                         do_sort ? perm : (const int*)nullptr,
                                         n, nb8 >> 3);
}

// Round 7
// 146.192 us; speedup vs baseline: 2.2082x; 2.2082x over previous
//
#include <hip/hip_runtime.h>
#include <math.h>

// TOF PET forward projection.
// History: R3 97us proj, FETCH 215MB (L2 thrash) -> R4 Morton sort: FETCH
// 26MB. R5 thread-per-LOR: proj ~107us (no gain; latency-chain bound at 12
// waves/CU) and bucket_kernel exploded to 146us: all invalid LORs atomicAdd'd
// ONE bucket -> same-address RMW serialization (VALUBusy 0.85%).
// R6: (a) invalids spread uniformly across buckets (they exit proj instantly;
// locality unaffected); (b) 4 lanes per LOR, sample stride 4: 32 waves/CU,
// ~10 trips/lane, shfl_xor(1,2) combine. Per-(LOR,sample) math bit-identical;
// only summation order changes (proven invisible on the bf16 grid: R4
// butterfly vs R5 sequential both absmax 0.015625).
// Index-path math is STRICTLY UNFUSED exact-rn f32 (numpy semantics) — DO NOT
// approximate or contract (R0-R2: FMA/ulp deviations => voxel flips =>
// absmax 0.14 > 0.071 threshold). fp contract(off) + plain ops + plain '/'.

#define NB_POS 4096          // 16^3 Morton cells, 25 mm
#define NCLS   4             // window-length classes (32-sample bins)
#define NBUCK  (NB_POS * NCLS)
#define SPL    4             // lanes per LOR

__device__ __forceinline__ int morton4(int x, int y, int z) {
    int m = 0;
#pragma unroll
    for (int b = 0; b < 4; ++b) {
        m |= ((x >> b) & 1) << (3 * b + 0);
        m |= ((y >> b) & 1) << (3 * b + 1);
        m |= ((z >> b) & 1) << (3 * b + 2);
    }
    return m;
}

__global__ void bucket_kernel(const float* __restrict__ lors,
                              int* __restrict__ counts,
                              int* __restrict__ tmp, int n) {
    int i = blockIdx.x * 256 + threadIdx.x;
    if (i >= n) return;
    const float* lp = lors + (size_t)i * 7;
    float p1x = lp[0], p1y = lp[1], p1z = lp[2];
    float dx = lp[3] - p1x, dy = lp[4] - p1y, dz = lp[5] - p1z;
    float tt = lp[6];
    float L = sqrtf(dx * dx + dy * dy + dz * dz);

    const float eps = 1e-8f;
    float sdx = (fabsf(dx) < eps) ? eps : dx;
    float sdy = (fabsf(dy) < eps) ? eps : dy;
    float sdz = (fabsf(dz) < eps) ? eps : dz;
    float tax = (-200.f - p1x) / sdx, tbx = (200.f - p1x) / sdx;
    float tay = (-200.f - p1y) / sdy, tby = (200.f - p1y) / sdy;
    float taz = (-200.f - p1z) / sdz, tbz = (200.f - p1z) / sdz;
    float tmin = fmaxf(fmaxf(fmaxf(fminf(tax, tbx), fminf(tay, tby)),
                             fminf(taz, tbz)), 0.f);
    float tmax = fminf(fminf(fminf(fmaxf(tax, tbx), fmaxf(tay, tby)),
                             fmaxf(taz, tbz)), 1.f);

    unsigned key;
    if (!(tmax > tmin) || !(L > 0.f)) {
        // Invalid LORs: spread uniformly over all buckets. They exit proj
        // before any gather, so locality is unaffected; this kills the
        // single-hot-bucket atomic serialization that cost 146us in R5.
        key = (unsigned)i & (NBUCK - 1);
    } else {
        float span = tmax - tmin;
        // in-box TOF-center point -> 25mm Morton cell (sort key only; approx ok)
        float tc = fminf(fmaxf(0.5f + tt / L, tmin), tmax);
        float px = p1x + tc * dx, py = p1y + tc * dy, pz = p1z + tc * dz;
        int cx = (int)fminf(fmaxf((px + 200.f) * 0.04f, 0.f), 15.f);
        int cy = (int)fminf(fmaxf((py + 200.f) * 0.04f, 0.f), 15.f);
        int cz = (int)fminf(fmaxf((pz + 200.f) * 0.04f, 0.f), 15.f);
        // window length (samples) -> 2-bit class, equalizes wave trip counts
        float jl = ((0.5f + (tt - 90.f) / L) - tmin) / span * 128.f;
        float jh = ((0.5f + (tt + 90.f) / L) - tmin) / span * 128.f;
        jl = fmaxf(jl, 0.f); jh = fminf(jh, 128.f);
        float wlen = fmaxf(jh - jl, 0.f);
        int cls = min(NCLS - 1, (int)(wlen * (1.f / 32.f)));
        key = ((unsigned)morton4(cx, cy, cz) << 2) | (unsigned)cls;
    }
    unsigned r = (unsigned)atomicAdd(&counts[key], 1);
    tmp[i] = (int)((key << 18) | r);           // n < 2^18
}

__global__ void scan_kernel(const int* __restrict__ counts,
                            int* __restrict__ offsets) {
    __shared__ int s[1024];
    int t = threadIdx.x;
    int base = t * (NBUCK / 1024);
    int local[NBUCK / 1024];
    int sum = 0;
#pragma unroll
    for (int i = 0; i < NBUCK / 1024; ++i) { local[i] = counts[base + i]; sum += local[i]; }
    s[t] = sum;
    __syncthreads();
    for (int off = 1; off < 1024; off <<= 1) {
        int v = (t >= off) ? s[t - off] : 0;
        __syncthreads();
        s[t] += v;
        __syncthreads();
    }
    int excl = (t == 0) ? 0 : s[t - 1];
#pragma unroll
    for (int i = 0; i < NBUCK / 1024; ++i) { offsets[base + i] = excl; excl += local[i]; }
}

__global__ void scatter_kernel(const int* __restrict__ tmp,
                               const int* __restrict__ offsets,
                               int* __restrict__ perm, int n) {
    int i = blockIdx.x * 256 + threadIdx.x;
    if (i >= n) return;
    unsigned v = (unsigned)tmp[i];
    perm[offsets[v >> 18] + (v & 0x3FFFFu)] = i;
}

__global__ __launch_bounds__(256) void proj_kernel(
    const float* __restrict__ image,
    const float* __restrict__ lors,
    float* __restrict__ out,
    const int* __restrict__ perm,
    int n_lors, int chunks)
{
#pragma clang fp contract(off)
    // XCD swizzle: block b -> XCD (b&7) works the (b&7)-th chunk of sorted order
    const int b = blockIdx.x;
    const int sb = (b & 7) * chunks + (b >> 3);
    const int base = sb * 256 + (int)threadIdx.x;
    const int gid = base >> 2;         // LOR slot in sorted order
    const int s   = base & 3;          // sub-lane 0..3 of this LOR
    if (gid >= n_lors) return;
    const int lor = perm ? perm[gid] : gid;

    const float* lp = lors + (size_t)lor * 7;
    const float p1x = lp[0], p1y = lp[1], p1z = lp[2];
    const float p2x = lp[3], p2y = lp[4], p2z = lp[5];
    const float ttof = lp[6];

    const float dx = p2x - p1x;
    const float dy = p2y - p1y;
    const float dz = p2z - p1z;

    // numpy order, unfused
    const float L = sqrtf(((dx * dx) + (dy * dy)) + (dz * dz));

    const float eps = 1e-8f;
    const float sdx = (fabsf(dx) < eps) ? eps : dx;
    const float sdy = (fabsf(dy) < eps) ? eps : dy;
    const float sdz = (fabsf(dz) < eps) ? eps : dz;

    // slab intersection, exact rn division (feeds the index path!)
    const float tax = (-200.0f - p1x) / sdx;
    const float tbx = ( 200.0f - p1x) / sdx;
    const float tay = (-200.0f - p1y) / sdy;
    const float tby = ( 200.0f - p1y) / sdy;
    const float taz = (-200.0f - p1z) / sdz;
    const float tbz = ( 200.0f - p1z) / sdz;

    const float tmin = fmaxf(fmaxf(fmaxf(fminf(tax, tbx), fminf(tay, tby)),
                                   fminf(taz, tbz)), 0.0f);
    const float tmax = fminf(fminf(fminf(fmaxf(tax, tbx), fmaxf(tay, tby)),
                                   fmaxf(taz, tbz)), 1.0f);
    const float span = fmaxf(tmax - tmin, 0.0f);

    if (!(tmax > tmin)) {
        if (s == 0) out[lor] = 0.0f;
        return;
    }

    // Closed-form sample range of TOF window (+-2 slop, validated R4/R5;
    // exact per-sample test retained below -> bit-identical voxel/weight set).
    int jlo = 0, jhi = 127;
    if (L > 0.0f) {
        const float tlo = 0.5f + (ttof - 90.0f) / L;
        const float thi = 0.5f + (ttof + 90.0f) / L;
        float jl = ((tlo - tmin) / span) * 128.0f - 0.5f;
        float jh = ((thi - tmin) / span) * 128.0f - 0.5f;
        jl = fminf(fmaxf(jl - 2.0f, 0.0f), 127.0f);
        jh = fminf(fmaxf(jh + 2.0f, -1.0f), 127.0f);
        jlo = (int)jl;
        jhi = (int)ceilf(jh);
        if (jhi > 127) jhi = 127;
    }

    float acc = 0.0f;
    for (int j = jlo + s; j <= jhi; j += SPL) {
        const float frac = ((float)j + 0.5f) / 128.0f;       // exact
        const float t = tmin + (frac * span);                 // UNFUSED
        const float dev = ((t - 0.5f) * L) - ttof;            // unfused

        if (fabsf(dev) <= 90.0f) {
            const float px = p1x + (t * dx);                  // UNFUSED
            const float py = p1y + (t * dy);
            const float pz = p1z + (t * dz);
            int vx = (int)floorf((px + 200.0f) / 3.125f);     // exact rn div
            int vy = (int)floorf((py + 200.0f) / 3.125f);
            int vz = (int)floorf((pz + 200.0f) / 3.125f);
            vx = min(max(vx, 0), 127);
            vy = min(max(vy, 0), 127);
            vz = min(max(vz, 0), 127);

            const float val = image[(((vx << 7) | vy) << 7) | vz];

            const float w = 0.06649038f *
                            __expf(((-0.5f * dev) * dev) / 900.0f);
            acc += val * w;
        }
    }

    // combine the 4 sub-lanes of this LOR (summation order != reference;
    // invisible on the bf16 comparison grid — validated R4 vs R5)
    acc += __shfl_xor(acc, 1, 64);
    acc += __shfl_xor(acc, 2, 64);

    if (s == 0) {
        const float step = (span * L) / 128.0f;
        out[lor] = acc * step;
    }
}

extern "C" void kernel_launch(void* const* d_in, const int* in_sizes, int n_in,
                              void* d_out, int out_size, void* d_ws, size_t ws_size,
                              hipStream_t stream) {
    const float* image = (const float*)d_in[0];   // 128^3 fp32
    const float* lors  = (const float*)d_in[1];   // N x 7 fp32
    float* out = (float*)d_out;                   // N fp32
    const int n = in_sizes[1] / 7;

    int* counts  = (int*)d_ws;
    int* offsets = counts + NBUCK;
    int* tmp     = offsets + NBUCK;
    int* perm    = tmp + n;
    const size_t need = (size_t)(2 * NBUCK + 2 * n) * sizeof(int);
    const bool do_sort = (ws_size >= need) && (n < (1 << 18));

    const int nthreads = n * SPL;
    const int nblocks = (nthreads + 255) / 256;
    const int nb8 = ((nblocks + 7) / 8) * 8;

    if (do_sort) {
        hipMemsetAsync(counts, 0, NBUCK * sizeof(int), stream);
        bucket_kernel<<<(n + 255) / 256, 256, 0, stream>>>(lors, counts, tmp, n);
        scan_kernel<<<1, 1024, 0, stream>>>(counts, offsets);
        scatter_kernel<<<(n + 255) / 256, 256, 0, stream>>>(tmp, offsets, perm, n);
    }
    proj_kernel<<<nb8, 256, 0, stream>>>(image, lors, out,
                                         do_sort ? perm : (const int*)nullptr,
                                         n, nb8 >> 3);
}

// Round 8
// 144.308 us; speedup vs baseline: 2.2370x; 1.0130x over previous
//
#include <hip/hip_runtime.h>
#include <math.h>

// TOF PET forward projection.
// History: R3 97us proj, FETCH 215MB (L2 thrash) -> R4 Morton sort: FETCH
// 26MB -> R5 bucket atomic-storm bug (146us) -> R6 fix + 4 lanes/LOR: proj
// 67us, total 146us. R6 proved proj is latency-bound, not VALU-bound (more
// total work than R5 but 1.6x faster).
// R7: (a) scatter materializes SORTED ray records (tmin/span/L/jlo/jhi +
// p1/p2/tof/orig) so proj has zero setup and coalesced LOR reads; (b) 8
// lanes/LOR (~3x wave oversubscription, ~4 trips/lane); (c) /128 -> *0.0078125
// (bit-identical, power of 2) and /900 -> mul (weight path, invisible on bf16
// comparison grid). The 3 voxel /3.125 divides stay IEEE '/' (index-critical).
// Index-path math is STRICTLY UNFUSED exact-rn f32 (numpy semantics) — DO NOT
// approximate or contract (R0-R2: FMA/ulp deviations => voxel flips =>
// absmax 0.14 > 0.071 threshold). fp contract(off) + plain ops + plain '/'.
// Summation order is free (R4 butterfly / R5 sequential / R6 4-lane tree all
// scored absmax 0.015625 = 1 bf16 ulp comparison floor).

#define NB_POS 4096          // 16^3 Morton cells, 25 mm
#define NCLS   8             // window-length classes (16-sample bins)
#define NBUCK  (NB_POS * NCLS)
#define SPL    8             // lanes per LOR

__device__ __forceinline__ int morton4(int x, int y, int z) {
    int m = 0;
#pragma unroll
    for (int b = 0; b < 4; ++b) {
        m |= ((x >> b) & 1) << (3 * b + 0);
        m |= ((y >> b) & 1) << (3 * b + 1);
        m |= ((z >> b) & 1) << (3 * b + 2);
    }
    return m;
}

// Slab clip shared by bucket/scatter (strictly unfused, exact rn divs —
// produces the tmin/span the reference sees).
__device__ __forceinline__ void slab_clip(
    float p1x, float p1y, float p1z, float dx, float dy, float dz,
    float& tmin, float& tmax)
{
    const float eps = 1e-8f;
    float sdx = (fabsf(dx) < eps) ? eps : dx;
    float sdy = (fabsf(dy) < eps) ? eps : dy;
    float sdz = (fabsf(dz) < eps) ? eps : dz;
    float tax = (-200.f - p1x) / sdx, tbx = (200.f - p1x) / sdx;
    float tay = (-200.f - p1y) / sdy, tby = (200.f - p1y) / sdy;
    float taz = (-200.f - p1z) / sdz, tbz = (200.f - p1z) / sdz;
    tmin = fmaxf(fmaxf(fmaxf(fminf(tax, tbx), fminf(tay, tby)),
                       fminf(taz, tbz)), 0.f);
    tmax = fminf(fminf(fminf(fmaxf(tax, tbx), fmaxf(tay, tby)),
                       fmaxf(taz, tbz)), 1.f);
}

__global__ void bucket_kernel(const float* __restrict__ lors,
                              int* __restrict__ counts,
                              int* __restrict__ tmp, int n) {
#pragma clang fp contract(off)
    int i = blockIdx.x * 256 + threadIdx.x;
    if (i >= n) return;
    const float* lp = lors + (size_t)i * 7;
    float p1x = lp[0], p1y = lp[1], p1z = lp[2];
    float dx = lp[3] - p1x, dy = lp[4] - p1y, dz = lp[5] - p1z;
    float tt = lp[6];
    float L = sqrtf(((dx * dx) + (dy * dy)) + (dz * dz));

    float tmin, tmax;
    slab_clip(p1x, p1y, p1z, dx, dy, dz, tmin, tmax);

    unsigned key;
    if (!(tmax > tmin) || !(L > 0.f)) {
        // Invalids: spread uniformly (kills R5's one-bucket atomic storm).
        key = (unsigned)i & (NBUCK - 1);
    } else {
        float span = tmax - tmin;
        // TOF-center cell (sort key only; approx math OK here)
        float tc = fminf(fmaxf(0.5f + tt / L, tmin), tmax);
        float px = p1x + tc * dx, py = p1y + tc * dy, pz = p1z + tc * dz;
        int cx = (int)fminf(fmaxf((px + 200.f) * 0.04f, 0.f), 15.f);
        int cy = (int)fminf(fmaxf((py + 200.f) * 0.04f, 0.f), 15.f);
        int cz = (int)fminf(fmaxf((pz + 200.f) * 0.04f, 0.f), 15.f);
        // window length -> 3-bit class (16-sample bins): wave-uniform trips
        float jl = ((0.5f + (tt - 90.f) / L) - tmin) / span * 128.f;
        float jh = ((0.5f + (tt + 90.f) / L) - tmin) / span * 128.f;
        jl = fmaxf(jl, 0.f); jh = fminf(jh, 128.f);
        float wlen = fmaxf(jh - jl, 0.f);
        int cls = min(NCLS - 1, (int)(wlen * (1.f / 16.f)));
        key = ((unsigned)morton4(cx, cy, cz) << 3) | (unsigned)cls;
    }
    atomicAdd(&counts[key], 1);
    tmp[i] = (int)key;
}

__global__ void scan_kernel(const int* __restrict__ counts,
                            int* __restrict__ offsets) {
    __shared__ int s[1024];
    int t = threadIdx.x;
    const int PER = NBUCK / 1024;
    int base = t * PER;
    int local[PER];
    int sum = 0;
#pragma unroll
    for (int i = 0; i < PER; ++i) { local[i] = counts[base + i]; sum += local[i]; }
    s[t] = sum;
    __syncthreads();
    for (int off = 1; off < 1024; off <<= 1) {
        int v = (t >= off) ? s[t - off] : 0;
        __syncthreads();
        s[t] += v;
        __syncthreads();
    }
    int excl = (t == 0) ? 0 : s[t - 1];
#pragma unroll
    for (int i = 0; i < PER; ++i) { offsets[base + i] = excl; excl += local[i]; }
}

// Scatter + setup: computes per-LOR ray record once, writes SORTED arrays.
__global__ void scatter_kernel(const float* __restrict__ lors,
                               const int* __restrict__ tmp,
                               int* __restrict__ offsets,
                               float4* __restrict__ recS,   // {tmin,span,L,pack}
                               float4* __restrict__ ls8,    // 2 per LOR
                               int n) {
#pragma clang fp contract(off)
    int i = blockIdx.x * 256 + threadIdx.x;
    if (i >= n) return;
    const float* lp = lors + (size_t)i * 7;
    float p1x = lp[0], p1y = lp[1], p1z = lp[2];
    float p2x = lp[3], p2y = lp[4], p2z = lp[5];
    float tt = lp[6];
    float dx = p2x - p1x, dy = p2y - p1y, dz = p2z - p1z;
    float L = sqrtf(((dx * dx) + (dy * dy)) + (dz * dz));

    float tmin, tmax;
    slab_clip(p1x, p1y, p1z, dx, dy, dz, tmin, tmax);

    float span, recL;
    int jlo, jhi;
    if (!(tmax > tmin) || !(L > 0.f)) {
        // invalid or degenerate (L==0 => step==0 => out 0 regardless)
        tmin = 0.f; span = 0.f; recL = 0.f; jlo = 0; jhi = -1;
    } else {
        span = tmax - tmin;
        recL = L;
        // Closed-form sample range of TOF window, +-2 slop (validated R4-R6);
        // exact per-sample test retained in proj -> identical sample set.
        const float tlo = 0.5f + (tt - 90.0f) / L;
        const float thi = 0.5f + (tt + 90.0f) / L;
        float jl = ((tlo - tmin) / span) * 128.0f - 0.5f;
        float jh = ((thi - tmin) / span) * 128.0f - 0.5f;
        jl = fminf(fmaxf(jl - 2.0f, 0.0f), 127.0f);
        jh = fminf(fmaxf(jh + 2.0f, -1.0f), 127.0f);
        jlo = (int)jl;
        jhi = (int)ceilf(jh);
        if (jhi > 127) jhi = 127;
    }

    int slot = atomicAdd(&offsets[tmp[i]], 1);
    int pk = (jlo << 16) | (jhi & 0xFFFF);
    recS[slot] = make_float4(tmin, span, recL, __int_as_float(pk));
    ls8[2 * slot + 0] = make_float4(p1x, p1y, p1z, p2x);
    ls8[2 * slot + 1] = make_float4(p2y, p2z, tt, __int_as_float(i));
}

__global__ __launch_bounds__(256) void proj_kernel(
    const float* __restrict__ image,
    const float4* __restrict__ recS,
    const float4* __restrict__ ls8,
    float* __restrict__ out,
    int n_lors, int chunks)
{
#pragma clang fp contract(off)
    // XCD swizzle: block b -> XCD (b&7) works the (b&7)-th chunk of sorted order
    const int b = blockIdx.x;
    const int sb = (b & 7) * chunks + (b >> 3);
    const int idx = sb * 256 + (int)threadIdx.x;
    const int gid = idx >> 3;          // sorted LOR slot
    const int s   = idx & 7;           // sub-lane 0..7
    if (gid >= n_lors) return;

    const float4 a  = ls8[2 * gid + 0];
    const float4 c  = ls8[2 * gid + 1];
    const float4 r  = recS[gid];
    const float p1x = a.x, p1y = a.y, p1z = a.z;
    const float dx = a.w - p1x, dy = c.x - p1y, dz = c.y - p1z;
    const float ttof = c.z;
    const int   orig = __float_as_int(c.w);
    const float tmin = r.x, span = r.y, L = r.z;
    const int   pk   = __float_as_int(r.w);
    const int   jlo  = pk >> 16;
    const int   jhi  = (int)(short)(pk & 0xFFFF);

    float acc = 0.0f;
    for (int j = jlo + s; j <= jhi; j += SPL) {
        // frac = (j+0.5)/128: *0.0078125f is bit-identical (power of 2)
        const float frac = ((float)j + 0.5f) * 0.0078125f;
        const float t = tmin + (frac * span);                 // UNFUSED
        const float dev = ((t - 0.5f) * L) - ttof;            // unfused

        if (fabsf(dev) <= 90.0f) {
            const float px = p1x + (t * dx);                  // UNFUSED
            const float py = p1y + (t * dy);
            const float pz = p1z + (t * dz);
            int vx = (int)floorf((px + 200.0f) / 3.125f);     // exact rn div
            int vy = (int)floorf((py + 200.0f) / 3.125f);
            int vz = (int)floorf((pz + 200.0f) / 3.125f);
            vx = min(max(vx, 0), 127);
            vy = min(max(vy, 0), 127);
            vz = min(max(vz, 0), 127);

            const float val = image[(((vx << 7) | vy) << 7) | vz];

            // weight path: invisible on bf16 grid; -1/1800 as multiply
            const float w = 0.06649038f *
                            __expf((dev * dev) * (-5.5555556e-4f));
            acc += val * w;
        }
    }

    // combine 8 sub-lanes (summation order free — validated R4/R5/R6)
    acc += __shfl_xor(acc, 1, 64);
    acc += __shfl_xor(acc, 2, 64);
    acc += __shfl_xor(acc, 4, 64);

    if (s == 0) {
        // step = (span*L)/128: *0.0078125f bit-identical
        const float step = (span * L) * 0.0078125f;
        out[orig] = acc * step;
    }
}

// Fallback (ws too small): self-contained thread-per-LOR, unsorted. Correct
// but slower; only taken if the harness workspace is < ~11 MB.
__global__ __launch_bounds__(256) void proj_fallback(
    const float* __restrict__ image,
    const float* __restrict__ lors,
    float* __restrict__ out, int n_lors)
{
#pragma clang fp contract(off)
    const int lor = blockIdx.x * 256 + threadIdx.x;
    if (lor >= n_lors) return;
    const float* lp = lors + (size_t)lor * 7;
    const float p1x = lp[0], p1y = lp[1], p1z = lp[2];
    const float dx = lp[3] - p1x, dy = lp[4] - p1y, dz = lp[5] - p1z;
    const float ttof = lp[6];
    const float L = sqrtf(((dx * dx) + (dy * dy)) + (dz * dz));
    float tmin, tmax;
    slab_clip(p1x, p1y, p1z, dx, dy, dz, tmin, tmax);
    const float span = fmaxf(tmax - tmin, 0.0f);
    if (!(tmax > tmin)) { out[lor] = 0.0f; return; }
    float acc = 0.0f;
    for (int j = 0; j < 128; ++j) {
        const float frac = ((float)j + 0.5f) * 0.0078125f;
        const float t = tmin + (frac * span);
        const float dev = ((t - 0.5f) * L) - ttof;
        if (fabsf(dev) <= 90.0f) {
            const float px = p1x + (t * dx);
            const float py = p1y + (t * dy);
            const float pz = p1z + (t * dz);
            int vx = (int)floorf((px + 200.0f) / 3.125f);
            int vy = (int)floorf((py + 200.0f) / 3.125f);
            int vz = (int)floorf((pz + 200.0f) / 3.125f);
            vx = min(max(vx, 0), 127);
            vy = min(max(vy, 0), 127);
            vz = min(max(vz, 0), 127);
            const float val = image[(((vx << 7) | vy) << 7) | vz];
            const float w = 0.06649038f *
                            __expf((dev * dev) * (-5.5555556e-4f));
            acc += val * w;
        }
    }
    out[lor] = acc * ((span * L) * 0.0078125f);
}

extern "C" void kernel_launch(void* const* d_in, const int* in_sizes, int n_in,
                              void* d_out, int out_size, void* d_ws, size_t ws_size,
                              hipStream_t stream) {
    const float* image = (const float*)d_in[0];   // 128^3 fp32
    const float* lors  = (const float*)d_in[1];   // N x 7 fp32
    float* out = (float*)d_out;                   // N fp32
    const int n = in_sizes[1] / 7;

    // ws layout: counts[NBUCK] | offsets[NBUCK] | tmp[n] | (16B align)
    //            recS[n]x16B | ls8[2n]x16B
    char* base = (char*)d_ws;
    int* counts  = (int*)base;
    int* offsets = counts + NBUCK;
    int* tmp     = offsets + NBUCK;
    size_t off = (size_t)(2 * NBUCK + n) * sizeof(int);
    off = (off + 15) & ~(size_t)15;
    float4* recS = (float4*)(base + off);
    float4* ls8  = (float4*)(base + off + (size_t)n * 16);
    const size_t need = off + (size_t)n * 48;
    const bool do_sort = (ws_size >= need);

    if (do_sort) {
        hipMemsetAsync(counts, 0, NBUCK * sizeof(int), stream);
        bucket_kernel<<<(n + 255) / 256, 256, 0, stream>>>(lors, counts, tmp, n);
        scan_kernel<<<1, 1024, 0, stream>>>(counts, offsets);
        scatter_kernel<<<(n + 255) / 256, 256, 0, stream>>>(lors, tmp, offsets,
                                                            recS, ls8, n);
        const int nthreads = n * SPL;
        const int nblocks = (nthreads + 255) / 256;
        const int nb8 = ((nblocks + 7) / 8) * 8;
        proj_kernel<<<nb8, 256, 0, stream>>>(image, recS, ls8, out, n, nb8 >> 3);
    } else {
        proj_fallback<<<(n + 255) / 256, 256, 0, stream>>>(image, lors, out, n);
    }
}